// Round 18
// baseline (7798.611 us; speedup 1.0000x reference)
//
#include <hip/hip_runtime.h>
#include <hip/hip_bf16.h>
#include <math.h>
#include <stdint.h>

typedef long long ll;

// ---------------- threefry2x32 (20 rounds, JAX/Random123 exact) ----------------
__host__ __device__ inline uint32_t rotl32(uint32_t v, int d) { return (v << d) | (v >> (32 - d)); }

#define TF_R4(a, b, c, d)                              \
  x0 += x1; x1 = rotl32(x1, a); x1 ^= x0;              \
  x0 += x1; x1 = rotl32(x1, b); x1 ^= x0;              \
  x0 += x1; x1 = rotl32(x1, c); x1 ^= x0;              \
  x0 += x1; x1 = rotl32(x1, d); x1 ^= x0;

__host__ __device__ inline void threefry(uint32_t k0, uint32_t k1, uint32_t x0, uint32_t x1,
                                         uint32_t* o0, uint32_t* o1) {
  uint32_t ks2 = k0 ^ k1 ^ 0x1BD11BDAu;
  x0 += k0; x1 += k1;
  TF_R4(13, 15, 26, 6)
  x0 += k1; x1 += ks2 + 1u;
  TF_R4(17, 29, 16, 24)
  x0 += ks2; x1 += k0 + 2u;
  TF_R4(13, 15, 26, 6)
  x0 += k0; x1 += k1 + 3u;
  TF_R4(17, 29, 16, 24)
  x0 += k1; x1 += ks2 + 4u;
  TF_R4(13, 15, 26, 6)
  x0 += ks2; x1 += k0 + 5u;
  *o0 = x0; *o1 = x1;
}

__device__ __forceinline__ float pe_val(int pos, int d) {
  int k2 = (d >> 1) << 1;
  float div = expf((float)k2 * (-9.210340371976184f / 512.0f));
  float arg = (float)pos * div;
  return (d & 1) ? cosf(arg) : sinf(arg);
}

// ---------------- kernels ----------------

// embed nb batches starting at b0 into out (local rows)
__global__ __launch_bounds__(256) void embed_kernel(const float* __restrict__ src,
                                                    const float* __restrict__ in_w,
                                                    const float* __restrict__ in_b,
                                                    int b0, int nb, float* __restrict__ out) {
  ll i = (ll)blockIdx.x * 256 + threadIdx.x;
  if (i >= (ll)nb * 2048 * 512) return;
  int d = (int)(i & 511);
  ll r = i >> 9;
  int l = (int)(r & 2047);
  int b = b0 + (int)(r >> 11);
  float acc = in_b[d];
#pragma unroll
  for (int j = 0; j < 6; j++)
    acc = fmaf(src[((ll)b * 2048 + l) * 6 + j], in_w[j * 512 + d], acc);
  acc += pe_val(l, d);
  out[i] = acc;
}

// R16b: LDS-tiled transpose of conv weights [o][i][tap] -> [tap][i][o].
// Coalesced load and store; 65-stride pad kills bank conflicts. Values only move;
// gemm's Bs contents are identical -> bitwise-identical conv outputs.
__global__ __launch_bounds__(256) void wt_kernel(const float* __restrict__ W,
                                                 float* __restrict__ WT,
                                                 ll srcOff) {
  __shared__ float tile[64][65];
  int o0 = blockIdx.x * 64, c0 = blockIdx.y * 64;
  int t = threadIdx.x;
  int g = t >> 6, l = t & 63;   // g:0..3, l:0..63
#pragma unroll 4
  for (int jj = 0; jj < 16; jj++) {
    int r = g * 16 + jj;
    tile[r][l] = W[srcOff + (ll)(o0 + r) * 1536 + (c0 + l)];
  }
  __syncthreads();
#pragma unroll 4
  for (int jj = 0; jj < 16; jj++) {
    int c = g * 16 + jj;
    int gc = c0 + c;
    int tap = gc % 3, k = gc / 3;
    WT[(ll)tap * 262144 + (ll)k * 512 + (o0 + l)] = tile[l][c];
  }
}

// 64x64-tile GEMM, 256 threads, 4x4 acc. C local rows. Grid (M/64, N/64).
// Verified R10/R11/R13: BK=32 single buffer (sweep: 16=9761, 32=best, 64=8552).
// Load idiom: float4 locals -> member-wise LDS stores; NO structs / NO
// address-of-register (R4-R8 scratch catastrophe; never reintroduce).
// R16b: wTapStride param — taps offset = tp*wTapStride (transposed [tap][k][n]
// takes the vectorized wSN==1 path; verified R17: -374us).
// fuse: 0 none, 1 gelu, 2 BN+ELU (bn_* indexed by column n).
__global__ __launch_bounds__(256, 4) void gemm_kernel(
    const float* __restrict__ A, int mBase, int L, int K,
    const float* __restrict__ W, ll wOffBase, int wSK, int wSN, int wTapStride,
    const float* __restrict__ bias, float* __restrict__ C, int N,
    int taps, int shiftMode, int fuse,
    const float* __restrict__ bn_g, const float* __restrict__ bn_b,
    const float* __restrict__ bn_m, const float* __restrict__ bn_v) {
  __shared__ float As[32][68];
  __shared__ float Bs[32][64];
  const int tid = threadIdx.x;
  const int tx = tid & 15, ty = tid >> 4;     // tx: 4 cols, ty: 4 rows
  const int m0 = blockIdx.x * 64, n0 = blockIdx.y * 64;
  const int rA = tid >> 2;                    // 0..63 loader row
  const int kA = (tid & 3) << 3;              // 0,8,16,24 (8 k per thread, 2 float4)
  const int kB = tid >> 4, nB0 = (tid & 15) << 2;  // B rows kB and kB+16

  float acc[4][4] = {};

  for (int tp = 0; tp < taps; tp++) {
    int shift = (taps == 3) ? tp - 1 : 0;
    int gRow = mBase + m0 + rA;
    int b = gRow / L, l = gRow - b * L;
    int l2 = l + shift;
    bool valid = true;
    if (shiftMode == 1) { valid = (l2 >= 0 && l2 < L); if (!valid) l2 = 0; }
    else if (shiftMode == 2) { l2 = l2 < 0 ? l2 + L : (l2 >= L ? l2 - L : l2); }
    const float* aRow = A + (ll)(b * L + l2) * K;
    const ll wOff = wOffBase + (taps == 3 ? (ll)tp * wTapStride : 0);

    for (int k0 = 0; k0 < K; k0 += 32) {
      float4 a0 = make_float4(0.f, 0.f, 0.f, 0.f);
      float4 a1 = make_float4(0.f, 0.f, 0.f, 0.f);
      if (valid) {
        a0 = *(const float4*)(aRow + k0 + kA);
        a1 = *(const float4*)(aRow + k0 + kA + 4);
      }
      As[kA + 0][rA] = a0.x; As[kA + 1][rA] = a0.y;
      As[kA + 2][rA] = a0.z; As[kA + 3][rA] = a0.w;
      As[kA + 4][rA] = a1.x; As[kA + 5][rA] = a1.y;
      As[kA + 6][rA] = a1.z; As[kA + 7][rA] = a1.w;
      if (wSN == 1) {
        *(float4*)&Bs[kB][nB0] = *(const float4*)(W + wOff + (ll)(k0 + kB) * wSK + (n0 + nB0));
        *(float4*)&Bs[kB + 16][nB0] = *(const float4*)(W + wOff + (ll)(k0 + kB + 16) * wSK + (n0 + nB0));
      } else {
#pragma unroll
        for (int j = 0; j < 4; j++)
          Bs[kB][nB0 + j] = W[wOff + (ll)(k0 + kB) * wSK + (ll)(n0 + nB0 + j) * wSN];
#pragma unroll
        for (int j = 0; j < 4; j++)
          Bs[kB + 16][nB0 + j] = W[wOff + (ll)(k0 + kB + 16) * wSK + (ll)(n0 + nB0 + j) * wSN];
      }
      __syncthreads();
#pragma unroll
      for (int kk = 0; kk < 32; kk++) {
        float4 w4 = *(const float4*)&Bs[kk][tx << 2];
        float4 a4 = *(const float4*)&As[kk][ty << 2];
        acc[0][0] = fmaf(a4.x, w4.x, acc[0][0]); acc[0][1] = fmaf(a4.x, w4.y, acc[0][1]);
        acc[0][2] = fmaf(a4.x, w4.z, acc[0][2]); acc[0][3] = fmaf(a4.x, w4.w, acc[0][3]);
        acc[1][0] = fmaf(a4.y, w4.x, acc[1][0]); acc[1][1] = fmaf(a4.y, w4.y, acc[1][1]);
        acc[1][2] = fmaf(a4.y, w4.z, acc[1][2]); acc[1][3] = fmaf(a4.y, w4.w, acc[1][3]);
        acc[2][0] = fmaf(a4.z, w4.x, acc[2][0]); acc[2][1] = fmaf(a4.z, w4.y, acc[2][1]);
        acc[2][2] = fmaf(a4.z, w4.z, acc[2][2]); acc[2][3] = fmaf(a4.z, w4.w, acc[2][3]);
        acc[3][0] = fmaf(a4.w, w4.x, acc[3][0]); acc[3][1] = fmaf(a4.w, w4.y, acc[3][1]);
        acc[3][2] = fmaf(a4.w, w4.z, acc[3][2]); acc[3][3] = fmaf(a4.w, w4.w, acc[3][3]);
      }
      __syncthreads();
    }
  }

  float4 bv = make_float4(0.f, 0.f, 0.f, 0.f);
  if (bias) bv = *(const float4*)(bias + n0 + (tx << 2));
  float4 g4, b4, m4, v4;
  if (fuse == 2) {
    g4 = *(const float4*)(bn_g + n0 + (tx << 2));
    b4 = *(const float4*)(bn_b + n0 + (tx << 2));
    m4 = *(const float4*)(bn_m + n0 + (tx << 2));
    v4 = *(const float4*)(bn_v + n0 + (tx << 2));
    v4.x = 1.f / sqrtf(v4.x + 1e-5f); v4.y = 1.f / sqrtf(v4.y + 1e-5f);
    v4.z = 1.f / sqrtf(v4.z + 1e-5f); v4.w = 1.f / sqrtf(v4.w + 1e-5f);
  }
#pragma unroll
  for (int i = 0; i < 4; i++) {
    int m = m0 + (ty << 2) + i;
    float4 v;
    v.x = acc[i][0] + bv.x; v.y = acc[i][1] + bv.y;
    v.z = acc[i][2] + bv.z; v.w = acc[i][3] + bv.w;
    if (fuse == 1) {
      v.x = 0.5f * v.x * (1.f + erff(v.x * 0.70710678118654752f));
      v.y = 0.5f * v.y * (1.f + erff(v.y * 0.70710678118654752f));
      v.z = 0.5f * v.z * (1.f + erff(v.z * 0.70710678118654752f));
      v.w = 0.5f * v.w * (1.f + erff(v.w * 0.70710678118654752f));
    } else if (fuse == 2) {
      v.x = (v.x - m4.x) * v4.x * g4.x + b4.x; v.x = v.x > 0.f ? v.x : expm1f(v.x);
      v.y = (v.y - m4.y) * v4.y * g4.y + b4.y; v.y = v.y > 0.f ? v.y : expm1f(v.y);
      v.z = (v.z - m4.z) * v4.z * g4.z + b4.z; v.z = v.z > 0.f ? v.z : expm1f(v.z);
      v.w = (v.w - m4.w) * v4.w * g4.w + b4.w; v.w = v.w > 0.f ? v.w : expm1f(v.w);
    }
    *(float4*)(C + (ll)m * N + n0 + (tx << 2)) = v;
  }
}

// merged q/k/v projection for one head, 64x64 tile: grid (rows/64, 3)
// R15-verified 3-block version (single-block merge regressed — occupancy beats
// traffic amortization in this launch regime).
__global__ __launch_bounds__(256, 4) void qkv_kernel(
    const float* __restrict__ X,
    const float* __restrict__ wq, const float* __restrict__ wk, const float* __restrict__ wv,
    ll wOff,
    const float* __restrict__ bq, const float* __restrict__ bk, const float* __restrict__ bv,
    float* __restrict__ QH, float* __restrict__ KH, float* __restrict__ VH) {
  const float* W; const float* bias; float* C;
  if (blockIdx.y == 0) { W = wq; bias = bq; C = QH; }
  else if (blockIdx.y == 1) { W = wk; bias = bk; C = KH; }
  else { W = wv; bias = bv; C = VH; }
  __shared__ float As[32][68];
  __shared__ float Bs[32][64];
  const int tid = threadIdx.x;
  const int tx = tid & 15, ty = tid >> 4;
  const int m0 = blockIdx.x * 64;
  const int rA = tid >> 2;
  const int kA = (tid & 3) << 3;
  const int kB = tid >> 4, nB0 = (tid & 15) << 2;
  const float* aRow = X + (ll)(m0 + rA) * 512;

  float acc[4][4] = {};
  for (int k0 = 0; k0 < 512; k0 += 32) {
    float4 a0 = *(const float4*)(aRow + k0 + kA);
    float4 a1 = *(const float4*)(aRow + k0 + kA + 4);
    As[kA + 0][rA] = a0.x; As[kA + 1][rA] = a0.y;
    As[kA + 2][rA] = a0.z; As[kA + 3][rA] = a0.w;
    As[kA + 4][rA] = a1.x; As[kA + 5][rA] = a1.y;
    As[kA + 6][rA] = a1.z; As[kA + 7][rA] = a1.w;
    *(float4*)&Bs[kB][nB0] = *(const float4*)(W + wOff + (ll)(k0 + kB) * 512 + nB0);
    *(float4*)&Bs[kB + 16][nB0] = *(const float4*)(W + wOff + (ll)(k0 + kB + 16) * 512 + nB0);
    __syncthreads();
#pragma unroll
    for (int kk = 0; kk < 32; kk++) {
      float4 w4 = *(const float4*)&Bs[kk][tx << 2];
      float4 a4 = *(const float4*)&As[kk][ty << 2];
      acc[0][0] = fmaf(a4.x, w4.x, acc[0][0]); acc[0][1] = fmaf(a4.x, w4.y, acc[0][1]);
      acc[0][2] = fmaf(a4.x, w4.z, acc[0][2]); acc[0][3] = fmaf(a4.x, w4.w, acc[0][3]);
      acc[1][0] = fmaf(a4.y, w4.x, acc[1][0]); acc[1][1] = fmaf(a4.y, w4.y, acc[1][1]);
      acc[1][2] = fmaf(a4.y, w4.z, acc[1][2]); acc[1][3] = fmaf(a4.y, w4.w, acc[1][3]);
      acc[2][0] = fmaf(a4.z, w4.x, acc[2][0]); acc[2][1] = fmaf(a4.z, w4.y, acc[2][1]);
      acc[2][2] = fmaf(a4.z, w4.z, acc[2][2]); acc[2][3] = fmaf(a4.z, w4.w, acc[2][3]);
      acc[3][0] = fmaf(a4.w, w4.x, acc[3][0]); acc[3][1] = fmaf(a4.w, w4.y, acc[3][1]);
      acc[3][2] = fmaf(a4.w, w4.z, acc[3][2]); acc[3][3] = fmaf(a4.w, w4.w, acc[3][3]);
    }
    __syncthreads();
  }
  float4 bv4 = *(const float4*)(bias + (tx << 2));
#pragma unroll
  for (int i = 0; i < 4; i++) {
    int m = m0 + (ty << 2) + i;
    float4 v;
    v.x = acc[i][0] + bv4.x; v.y = acc[i][1] + bv4.y;
    v.z = acc[i][2] + bv4.z; v.w = acc[i][3] + bv4.w;
    *(float4*)(C + (ll)m * 64 + (tx << 2)) = v;
  }
}

// JAX randint (pow2 span), partitionable mode: bits[m] = o0(k2;0,m)^o1(k2;0,m)
__global__ void idx_kernel(int* __restrict__ idx, uint32_t k0, uint32_t k1, int n, int mask) {
  int m = blockIdx.x * 256 + threadIdx.x;
  if (m < n) {
    uint32_t o0, o1;
    threefry(k0, k1, 0u, (uint32_t)m, &o0, &o1);
    idx[m] = (int)((o0 ^ o1) & (uint32_t)mask);
  }
}

// M[b,l] = max_u(q.k_samp) - sum_u(q.k_samp)/L
// R15/R16: 8-way ILP (verified; chain now gather-bound — axis closed).
// Cascading 8/4/2/1 loops; mx/sm updates strictly ascending in uu -> bitwise-identical M.
__global__ __launch_bounds__(256) void m_kernel(const float* __restrict__ Q,
                                                const float* __restrict__ Kk,
                                                const int* __restrict__ idx,
                                                float* __restrict__ M, int L, int U) {
  int wid = (int)(((ll)blockIdx.x * 256 + threadIdx.x) >> 6);
  int lane = threadIdx.x & 63;
  if (wid >= 8 * L) return;
  int b = wid / L, l = wid - b * L;
  float qv = Q[((ll)(b * L + l)) * 64 + lane];
  float mx = -INFINITY, sm = 0.f;
  const int* ip = idx + (ll)l * U;
  int uu = 0;
  for (; uu + 8 <= U; uu += 8) {
    int kr0 = ip[uu] & (L - 1);
    int kr1 = ip[uu + 1] & (L - 1);
    int kr2 = ip[uu + 2] & (L - 1);
    int kr3 = ip[uu + 3] & (L - 1);
    int kr4 = ip[uu + 4] & (L - 1);
    int kr5 = ip[uu + 5] & (L - 1);
    int kr6 = ip[uu + 6] & (L - 1);
    int kr7 = ip[uu + 7] & (L - 1);
    float p0 = qv * Kk[((ll)(b * L + kr0)) * 64 + lane];
    float p1 = qv * Kk[((ll)(b * L + kr1)) * 64 + lane];
    float p2 = qv * Kk[((ll)(b * L + kr2)) * 64 + lane];
    float p3 = qv * Kk[((ll)(b * L + kr3)) * 64 + lane];
    float p4 = qv * Kk[((ll)(b * L + kr4)) * 64 + lane];
    float p5 = qv * Kk[((ll)(b * L + kr5)) * 64 + lane];
    float p6 = qv * Kk[((ll)(b * L + kr6)) * 64 + lane];
    float p7 = qv * Kk[((ll)(b * L + kr7)) * 64 + lane];
#pragma unroll
    for (int d = 32; d > 0; d >>= 1) {
      p0 += __shfl_xor(p0, d);
      p1 += __shfl_xor(p1, d);
      p2 += __shfl_xor(p2, d);
      p3 += __shfl_xor(p3, d);
      p4 += __shfl_xor(p4, d);
      p5 += __shfl_xor(p5, d);
      p6 += __shfl_xor(p6, d);
      p7 += __shfl_xor(p7, d);
    }
    mx = fmaxf(mx, p0); sm += p0;
    mx = fmaxf(mx, p1); sm += p1;
    mx = fmaxf(mx, p2); sm += p2;
    mx = fmaxf(mx, p3); sm += p3;
    mx = fmaxf(mx, p4); sm += p4;
    mx = fmaxf(mx, p5); sm += p5;
    mx = fmaxf(mx, p6); sm += p6;
    mx = fmaxf(mx, p7); sm += p7;
  }
  for (; uu + 4 <= U; uu += 4) {
    int kr0 = ip[uu] & (L - 1);
    int kr1 = ip[uu + 1] & (L - 1);
    int kr2 = ip[uu + 2] & (L - 1);
    int kr3 = ip[uu + 3] & (L - 1);
    float p0 = qv * Kk[((ll)(b * L + kr0)) * 64 + lane];
    float p1 = qv * Kk[((ll)(b * L + kr1)) * 64 + lane];
    float p2 = qv * Kk[((ll)(b * L + kr2)) * 64 + lane];
    float p3 = qv * Kk[((ll)(b * L + kr3)) * 64 + lane];
#pragma unroll
    for (int d = 32; d > 0; d >>= 1) {
      p0 += __shfl_xor(p0, d);
      p1 += __shfl_xor(p1, d);
      p2 += __shfl_xor(p2, d);
      p3 += __shfl_xor(p3, d);
    }
    mx = fmaxf(mx, p0); sm += p0;
    mx = fmaxf(mx, p1); sm += p1;
    mx = fmaxf(mx, p2); sm += p2;
    mx = fmaxf(mx, p3); sm += p3;
  }
  for (; uu + 2 <= U; uu += 2) {
    int kr0 = ip[uu] & (L - 1);
    int kr1 = ip[uu + 1] & (L - 1);
    float p0 = qv * Kk[((ll)(b * L + kr0)) * 64 + lane];
    float p1 = qv * Kk[((ll)(b * L + kr1)) * 64 + lane];
#pragma unroll
    for (int d = 32; d > 0; d >>= 1) {
      p0 += __shfl_xor(p0, d);
      p1 += __shfl_xor(p1, d);
    }
    mx = fmaxf(mx, p0); sm += p0;
    mx = fmaxf(mx, p1); sm += p1;
  }
  if (uu < U) {
    int kr = ip[uu] & (L - 1);
    float p = qv * Kk[((ll)(b * L + kr)) * 64 + lane];
#pragma unroll
    for (int d = 32; d > 0; d >>= 1) p += __shfl_xor(p, d);
    mx = fmaxf(mx, p);
    sm += p;
  }
  if (lane == 0) M[(ll)b * L + l] = mx - sm / (float)L;
}

// fused: topk + qgather + vmean; one block per b.
// Register-resident M, shuffle-based argmax, one barrier per selected row (R2).
template <int NRT>
__global__ __launch_bounds__(256) void tgv_kernel(const float* __restrict__ M,
                                                  const float* __restrict__ Q,
                                                  const float* __restrict__ V,
                                                  int* __restrict__ topi,
                                                  float* __restrict__ QR,
                                                  float* __restrict__ vm, int L, int u) {
  __shared__ unsigned long long wbest[2][4];
  __shared__ int rows[40];
  __shared__ float s4[4][64];
  int b = blockIdx.x, t = threadIdx.x;
  int lane = t & 63, w = t >> 6;
  ll base = (ll)b * L;
  float v8[NRT];
#pragma unroll
  for (int i = 0; i < NRT; i++) v8[i] = M[base + t + (i << 8)];
  for (int j = 0; j < u; j++) {
    float bv = v8[0]; int bi = t;
#pragma unroll
    for (int i = 1; i < NRT; i++) {
      if (v8[i] > bv) { bv = v8[i]; bi = t + (i << 8); }
    }
    uint32_t mu = __float_as_uint(bv);
    mu = (mu & 0x80000000u) ? ~mu : (mu | 0x80000000u);
    unsigned long long key = ((unsigned long long)mu << 32) | (uint32_t)(~bi);
#pragma unroll
    for (int d = 32; d > 0; d >>= 1) {
      unsigned long long o = __shfl_xor(key, d);
      key = o > key ? o : key;
    }
    if (lane == 0) wbest[j & 1][w] = key;
    __syncthreads();
    unsigned long long k0 = wbest[j & 1][0], k1 = wbest[j & 1][1];
    unsigned long long k2 = wbest[j & 1][2], k3 = wbest[j & 1][3];
    unsigned long long kb = k0 > k1 ? k0 : k1;
    unsigned long long kc = k2 > k3 ? k2 : k3;
    if (kc > kb) kb = kc;
    int wi = (int)(~(uint32_t)kb);
#pragma unroll
    for (int i = 0; i < NRT; i++)
      if (wi == t + (i << 8)) v8[i] = -INFINITY;
    if (t == 0) { topi[(ll)b * u + j] = wi; rows[j] = wi; }
  }
  __syncthreads();
  for (int idx = t; idx < u * 64; idx += 256) {
    int j = idx >> 6, e = idx & 63;
    int row = rows[j];
    QR[((ll)b * u + j) * 64 + e] = Q[((ll)(b * L + row)) * 64 + e];
  }
  int e = t & 63, p2 = t >> 6;
  float acc = 0.f;
  for (int l = p2; l < L; l += 4) acc += V[((ll)(b * L + l)) * 64 + e];
  s4[p2][e] = acc;
  __syncthreads();
  if (t < 64)
    vm[(ll)b * 64 + t] = (s4[0][t] + s4[1][t] + s4[2][t] + s4[3][t]) / (float)L;
}

// ---- chunked attention ----
// R18: attna restructured grid (8u,C) -> (8, C): one block per (batch, chunk);
// each thread holds its K row in NAMED registers (krr0..15 — no arrays, scratch-safe)
// and loops all u queries (Q rows staged in LDS). Kills the u-fold redundant K
// streaming (L=2048: 164MB -> ~4MB per head). Dot order (e ascending, xyzw), 0.125
// scale, and the 64-lane shfl-max + 4-group max are IDENTICAL -> SC and MX bitwise
// identical -> attnb/attnc unchanged.
#define QKDOT(i) { float4 qq = q4[i]; \
  d = fmaf(qq.x, krr##i.x, d); d = fmaf(qq.y, krr##i.y, d); \
  d = fmaf(qq.z, krr##i.z, d); d = fmaf(qq.w, krr##i.w, d); }

__global__ __launch_bounds__(256) void attna_kernel(const float* __restrict__ QR,
                                                    const float* __restrict__ Kk,
                                                    float* __restrict__ SCb,
                                                    float* __restrict__ MX,
                                                    int L, int u) {
  int b = blockIdx.x, c = blockIdx.y;
  int t = threadIdx.x;
  int lane = t & 63, w = t >> 6;
  __shared__ float qs[40 * 64];
  __shared__ float wmax[2][4];
  for (int idx = t; idx < u * 64; idx += 256)
    qs[idx] = QR[(ll)(b * u) * 64 + idx];
  __syncthreads();
  int l = (c << 8) + t;
  const float4* kr = (const float4*)(Kk + ((ll)(b * L + l)) * 64);
  float4 krr0 = kr[0],  krr1 = kr[1],  krr2 = kr[2],  krr3 = kr[3];
  float4 krr4 = kr[4],  krr5 = kr[5],  krr6 = kr[6],  krr7 = kr[7];
  float4 krr8 = kr[8],  krr9 = kr[9],  krr10 = kr[10], krr11 = kr[11];
  float4 krr12 = kr[12], krr13 = kr[13], krr14 = kr[14], krr15 = kr[15];
  for (int j = 0; j < u; j++) {
    const float4* q4 = (const float4*)&qs[j << 6];
    float d = 0.f;
    QKDOT(0)  QKDOT(1)  QKDOT(2)  QKDOT(3)
    QKDOT(4)  QKDOT(5)  QKDOT(6)  QKDOT(7)
    QKDOT(8)  QKDOT(9)  QKDOT(10) QKDOT(11)
    QKDOT(12) QKDOT(13) QKDOT(14) QKDOT(15)
    d *= 0.125f;
    SCb[(ll)(b * u + j) * L + l] = d;
    float m = d;
#pragma unroll
    for (int s = 32; s > 0; s >>= 1) m = fmaxf(m, __shfl_xor(m, s));
    if (lane == 0) wmax[j & 1][w] = m;
    __syncthreads();
    if (t == 0)
      MX[(b * u + j) * 8 + c] =
          fmaxf(fmaxf(wmax[j & 1][0], wmax[j & 1][1]),
                fmaxf(wmax[j & 1][2], wmax[j & 1][3]));
  }
}

// attnb: grid (8u, C). exp(sc-mx), chunk denom, chunk PV partial.
__global__ __launch_bounds__(256) void attnb_kernel(const float* __restrict__ SCb,
                                                    const float* __restrict__ MX,
                                                    const float* __restrict__ V,
                                                    float* __restrict__ PUPD,
                                                    float* __restrict__ PSUM,
                                                    int L, int u, int C) {
  int g = blockIdx.x, c = blockIdx.y;
  int b = g / u;
  __shared__ float evs[256];
  __shared__ float red[256];
  __shared__ float upds[4][64];
  int t = threadIdx.x;
  float mx = MX[g * 8];
  for (int j = 1; j < C; j++) mx = fmaxf(mx, MX[g * 8 + j]);
  int l = (c << 8) + t;
  float ev = expf(SCb[(ll)g * L + l] - mx);
  evs[t] = ev;
  red[t] = ev;
  __syncthreads();
  for (int s = 128; s > 0; s >>= 1) { if (t < s) red[t] += red[t + s]; __syncthreads(); }
  int e = t & 63, p2 = t >> 6;
  const float* vb = V + ((ll)(b * L + (c << 8))) * 64;
  float partial = 0.f;
#pragma unroll 4
  for (int i = 0; i < 64; i++) {
    int lidx = p2 + (i << 2);
    partial = fmaf(evs[lidx], vb[(ll)lidx * 64 + e], partial);
  }
  upds[p2][e] = partial;
  __syncthreads();
  if (t < 64) {
    PUPD[((ll)(g * 8 + c)) * 64 + t] = upds[0][t] + upds[1][t] + upds[2][t] + upds[3][t];
    if (t == 0) PSUM[g * 8 + c] = red[0];
  }
}

// attnc: grid (8u), 64 threads: combine C chunks -> upd row.
__global__ __launch_bounds__(64) void attnc_kernel(const float* __restrict__ PUPD,
                                                   const float* __restrict__ PSUM,
                                                   float* __restrict__ upd, int C) {
  int g = blockIdx.x, t = threadIdx.x;
  float den = 0.f, val = 0.f;
  for (int c = 0; c < C; c++) {
    den += PSUM[g * 8 + c];
    val += PUPD[((ll)(g * 8 + c)) * 64 + t];
  }
  upd[(ll)g * 64 + t] = val * (1.f / den);
}

// BR[b,t] = bo[t] + sum_{h,e} VM[(h*8+b)*64+e] * Wo[wOff + (h*64+e)*512 + t]
__global__ __launch_bounds__(512) void baserow_kernel(const float* __restrict__ VM,
                                                      const float* __restrict__ Wo, ll wOff,
                                                      const float* __restrict__ bo,
                                                      float* __restrict__ BR) {
  int b = blockIdx.x, t = threadIdx.x;
  float acc = bo[t];
  for (int h = 0; h < 8; h++)
#pragma unroll 4
    for (int e = 0; e < 64; e++)
      acc = fmaf(VM[(ll)(h * 8 + b) * 64 + e], Wo[wOff + (ll)(h * 64 + e) * 512 + t], acc);
  BR[(ll)b * 512 + t] = acc;
}

// X[b, topi] += (upd - vm) @ Wo_h ; atomicAdd (rows may repeat across heads)
__global__ __launch_bounds__(512) void corr_kernel(const float* __restrict__ UPD,
                                                   const float* __restrict__ VM,
                                                   const int* __restrict__ topi,
                                                   const float* __restrict__ Wo, ll wOff,
                                                   float* __restrict__ X, int L, int u) {
  int g = blockIdx.x;
  int h = g / (8 * u);
  int r = g - h * 8 * u;
  int b = r / u;
  int row = topi[g] & (L - 1);
  int t = threadIdx.x;
  float c = 0.f;
#pragma unroll 4
  for (int e = 0; e < 64; e++) {
    float dv = UPD[(ll)g * 64 + e] - VM[(ll)(h * 8 + b) * 64 + e];
    c = fmaf(dv, Wo[wOff + (ll)(h * 64 + e) * 512 + t], c);
  }
  atomicAdd(&X[((ll)b * L + row) * 512 + t], c);
}

// layernorm over 512 of (x [+res] [+br(b)]); br is per-batch row (B x 512), b = row/L
__global__ __launch_bounds__(256) void ln_kernel(const float* __restrict__ x,
                                                 const float* __restrict__ res,
                                                 const float* __restrict__ br, int L,
                                                 const float* __restrict__ g,
                                                 const float* __restrict__ be,
                                                 float* __restrict__ out) {
  ll base = (ll)blockIdx.x * 512;
  int t = threadIdx.x;
  float v0 = x[base + t], v1 = x[base + 256 + t];
  if (res) { v0 += res[base + t]; v1 += res[base + 256 + t]; }
  if (br) {
    int b = blockIdx.x / L;
    v0 += br[(ll)b * 512 + t];
    v1 += br[(ll)b * 512 + 256 + t];
  }
  __shared__ float red[256];
  red[t] = v0 + v1;
  __syncthreads();
  for (int s = 128; s > 0; s >>= 1) { if (t < s) red[t] += red[t + s]; __syncthreads(); }
  float mu = red[0] * (1.f / 512.f);
  __syncthreads();
  float d0 = v0 - mu, d1 = v1 - mu;
  red[t] = d0 * d0 + d1 * d1;
  __syncthreads();
  for (int s = 128; s > 0; s >>= 1) { if (t < s) red[t] += red[t + s]; __syncthreads(); }
  float rstd = 1.f / sqrtf(red[0] * (1.f / 512.f) + 1e-5f);
  out[base + t] = d0 * rstd * g[t] + be[t];
  out[base + 256 + t] = d1 * rstd * g[t + 256] + be[t + 256];
}

// maxpool over nb local batches
__global__ __launch_bounds__(256) void maxpool_kernel(const float* __restrict__ y,
                                                      float* __restrict__ outp,
                                                      int L, int L2, int nb) {
  ll n = (ll)nb * L2 * 512;
  ll i = (ll)blockIdx.x * 256 + threadIdx.x;
  if (i >= n) return;
  int per = L2 * 512;
  int bb = (int)(i / per);
  int rem = (int)(i - (ll)bb * per);
  int c = rem & 511;
  int l2 = rem >> 9;
  int l0 = 2 * l2 - 1;
  float m = -INFINITY;
#pragma unroll
  for (int w = 0; w < 3; w++) {
    int l = l0 + w;
    if (l >= 0 && l < L) m = fmaxf(m, y[((ll)bb * L + l) * 512 + c]);
  }
  outp[i] = m;
}

// pred rows t=5..9
__global__ __launch_bounds__(64) void pred_kernel(const float* __restrict__ dec_b,
                                                  const float* __restrict__ head_w,
                                                  const float* __restrict__ head_b,
                                                  float* __restrict__ out) {
  int b = blockIdx.x / 5, tt = blockIdx.x % 5, t = 5 + tt;
  int lane = threadIdx.x;
  float a0 = 0.f, a1 = 0.f;
  for (int d = lane; d < 512; d += 64) {
    float td = dec_b[d] + pe_val(t, d) + pe_val(b, d);
    a0 = fmaf(td, head_w[2 * d], a0);
    a1 = fmaf(td, head_w[2 * d + 1], a1);
  }
#pragma unroll
  for (int s = 32; s > 0; s >>= 1) { a0 += __shfl_xor(a0, s); a1 += __shfl_xor(a1, s); }
  if (lane == 0) {
    out[(ll)b * 10 + tt * 2 + 0] = a0 + head_b[0];
    out[(ll)b * 10 + tt * 2 + 1] = a1 + head_b[1];
  }
}

// ---------------- host ----------------
extern "C" void kernel_launch(void* const* d_in, const int* in_sizes, int n_in,
                              void* d_out, int out_size, void* d_ws, size_t ws_size,
                              hipStream_t stream) {
  if (n_in < 34) return;
  if (in_sizes[0] != 8 * 2048 * 6) return;
  if (in_sizes[4] != 512 * 512 * 3) return;
  if (in_sizes[6] != 4 * 512 * 512) return;
  if (in_sizes[22] != 3 * 512 * 512 * 3) return;
  if (in_sizes[33] != 2) return;
  if (ws_size < 55700000) return;

  const ll BIG = (ll)8 * 2048 * 512;
  const ll HSZ = (ll)8 * 2048 * 64;
  const ll CSZ = (ll)2048 * 512;

  const float* src    = (const float*)d_in[0];
  const float* in_w   = (const float*)d_in[2];
  const float* in_b   = (const float*)d_in[3];
  const float* conv_w = (const float*)d_in[4];
  const float* conv_b = (const float*)d_in[5];
  const float* wq = (const float*)d_in[6];
  const float* bq = (const float*)d_in[7];
  const float* wk = (const float*)d_in[8];
  const float* bk = (const float*)d_in[9];
  const float* wv = (const float*)d_in[10];
  const float* bv = (const float*)d_in[11];
  const float* wo = (const float*)d_in[12];
  const float* bo = (const float*)d_in[13];
  const float* n1_g = (const float*)d_in[14];
  const float* n1_b = (const float*)d_in[15];
  const float* ff1_w = (const float*)d_in[16];
  const float* ff1_b = (const float*)d_in[17];
  const float* ff2_w = (const float*)d_in[18];
  const float* ff2_b = (const float*)d_in[19];
  const float* n2_g = (const float*)d_in[20];
  const float* n2_b = (const float*)d_in[21];
  const float* dconv_w = (const float*)d_in[22];
  const float* dconv_b = (const float*)d_in[23];
  const float* bn_g = (const float*)d_in[24];
  const float* bn_b = (const float*)d_in[25];
  const float* bn_m = (const float*)d_in[26];
  const float* bn_v = (const float*)d_in[27];
  const float* enc_g = (const float*)d_in[28];
  const float* enc_b = (const float*)d_in[29];
  const float* dec_bv = (const float*)d_in[31];
  const float* head_w = (const float*)d_in[32];
  const float* head_b = (const float*)d_in[33];
  float* out = (float*)d_out;

  char* p = (char*)d_ws;
  float* X  = (float*)p; p += BIG * 4;
  float* QH = (float*)p; p += HSZ * 4;   // pool start
  float* KH = (float*)p; p += HSZ * 4;
  float* VH = (float*)p; p += HSZ * 4;
  float* SC1 = (float*)p; p += CSZ * 4;
  float* SC2 = (float*)p; p += CSZ * 4;
  float* UPD = (float*)p; p += (ll)8 * 8 * 40 * 64 * 4;
  float* VM  = (float*)p; p += (ll)8 * 8 * 64 * 4;
  float* BR  = (float*)p; p += (ll)8 * 512 * 4;
  float* Mh  = (float*)p; p += (ll)8 * 2048 * 4;
  float* QR  = (float*)p; p += (ll)8 * 40 * 64 * 4;
  int* IDX   = (int*)p; p += (ll)2048 * 40 * 4;
  int* TOPIA = (int*)p;

  float* P0 = QH;                       // 4096x512 alias (QH+KH)
  float* P1 = QH + (ll)4096 * 512;      // 4096x512 alias (VH+SC1) — FFN phase only
  // attn scratch (h-loop only; temporally disjoint from P1's FFN use of SC1):
  float* MXf   = SC2;                   // 8u*8
  float* PSUMf = SC2 + 4096;            // 8u*8
  float* PUPDf = SC2 + 8192;            // 8u*8*64
  // transposed conv weights (SC2, conv/distill phases only — disjoint from attn scratch)
  float* WT = SC2;

  uint32_t keys[4][2];
  for (int i = 0; i < 4; i++) {
    uint32_t K0, K1, g0, g1;
    threefry(0u, 42u, 0u, (uint32_t)i, &K0, &K1);
    threefry(K0, K1, 0u, 1u, &g0, &g1);
    keys[i][0] = g0;
    keys[i][1] = g1;
  }

  // transpose input conv weights [o][i][tap] -> [tap][i][o] into SC2
  wt_kernel<<<dim3(8, 24), 256, 0, stream>>>(conv_w, WT, 0);
  // embed + input conv (zero-pad, 3 taps fused), 2 batches per iter through P0
  for (int bp = 0; bp < 4; bp++) {
    embed_kernel<<<(int)((2 * CSZ + 255) / 256), 256, 0, stream>>>(src, in_w, in_b, bp * 2, 2, P0);
    gemm_kernel<<<dim3(64, 8), 256, 0, stream>>>(
        P0, 0, 2048, 512, WT, 0, 512, 1, 262144, conv_b, X + (ll)bp * 2 * CSZ, 512,
        3, 1, 0, nullptr, nullptr, nullptr, nullptr);
  }

  const int Ls[4] = {2048, 1024, 512, 256};
  const int Us[4] = {40, 35, 35, 30};

  for (int i = 0; i < 4; i++) {
    int L = Ls[i], U = Us[i];
    int Mrows = 8 * L;
    int LU = L * U;
    int C = L >> 8;                      // 8,4,2,1 chunks of 256
    ll wOff = (ll)i * 262144;

    idx_kernel<<<(LU + 255) / 256, 256, 0, stream>>>(IDX, keys[i][0], keys[i][1], LU, L - 1);

    for (int h = 0; h < 8; h++) {
      qkv_kernel<<<dim3(Mrows / 64, 3), 256, 0, stream>>>(
          X, wq, wk, wv, wOff + h * 64,
          bq + i * 512 + h * 64, bk + i * 512 + h * 64, bv + i * 512 + h * 64, QH, KH, VH);
      m_kernel<<<(8 * L * 64) / 256, 256, 0, stream>>>(QH, KH, IDX, Mh, L, U);
      if (L == 2048)
        tgv_kernel<8><<<8, 256, 0, stream>>>(Mh, QH, VH, TOPIA + (ll)h * 8 * U, QR,
                                             VM + (ll)h * 8 * 64, L, U);
      else if (L == 1024)
        tgv_kernel<4><<<8, 256, 0, stream>>>(Mh, QH, VH, TOPIA + (ll)h * 8 * U, QR,
                                             VM + (ll)h * 8 * 64, L, U);
      else if (L == 512)
        tgv_kernel<2><<<8, 256, 0, stream>>>(Mh, QH, VH, TOPIA + (ll)h * 8 * U, QR,
                                             VM + (ll)h * 8 * 64, L, U);
      else
        tgv_kernel<1><<<8, 256, 0, stream>>>(Mh, QH, VH, TOPIA + (ll)h * 8 * U, QR,
                                             VM + (ll)h * 8 * 64, L, U);
      attna_kernel<<<dim3(8, C), 256, 0, stream>>>(QR, KH, SC1, MXf, L, U);
      attnb_kernel<<<dim3(8 * U, C), 256, 0, stream>>>(SC1, MXf, VH, PUPDf, PSUMf, L, U, C);
      attnc_kernel<<<8 * U, 64, 0, stream>>>(PUPDf, PSUMf, UPD + (ll)h * 8 * U * 64, C);
    }

    baserow_kernel<<<8, 512, 0, stream>>>(VM, wo, wOff, bo + i * 512, BR);
    corr_kernel<<<64 * U, 512, 0, stream>>>(UPD, VM, TOPIA, wo, wOff, X, L, U);
    // LN1 with BR folded in (X + corr + BR)
    ln_kernel<<<Mrows, 256, 0, stream>>>(X, nullptr, BR, L, n1_g + i * 512, n1_b + i * 512, X);

    // FFN: FF1+gelu -> P0; FF2 -> P1; LN2(X+P1) -> X  (4096-row chunks)
    int CR = Mrows < 4096 ? Mrows : 4096;
    for (int r0 = 0; r0 < Mrows; r0 += CR) {
      gemm_kernel<<<dim3(CR / 64, 8), 256, 0, stream>>>(
          X + (ll)r0 * 512, 0, CR, 512, ff1_w, wOff, 512, 1, 0, ff1_b + i * 512, P0, 512,
          1, 0, 1, nullptr, nullptr, nullptr, nullptr);
      gemm_kernel<<<dim3(CR / 64, 8), 256, 0, stream>>>(
          P0, 0, CR, 512, ff2_w, wOff, 512, 1, 0, ff2_b + i * 512, P1, 512,
          1, 0, 0, nullptr, nullptr, nullptr, nullptr);
      ln_kernel<<<CR, 256, 0, stream>>>(X + (ll)r0 * 512, P1, nullptr, L, n2_g + i * 512,
                                        n2_b + i * 512, X + (ll)r0 * 512);
    }

    if (i < 3) {
      // distill: conv(wrap,3 taps)+BN+ELU fused -> P0; maxpool -> X
      // transpose this layer's dconv weights into SC2 (attn scratch dead here)
      wt_kernel<<<dim3(8, 24), 256, 0, stream>>>(dconv_w, WT, (ll)i * 786432);
      int L2 = L / 2;
      int nbc = 4096 / L; if (nbc > 8) nbc = 8;   // 2, 4, 8
      for (int bp = 0; bp < 8 / nbc; bp++) {
        gemm_kernel<<<dim3((nbc * L) / 64, 8), 256, 0, stream>>>(
            X, bp * nbc * L, L, 512, WT, 0, 512, 1, 262144, dconv_b + i * 512,
            P0, 512, 3, 2, 2, bn_g + i * 512, bn_b + i * 512, bn_m + i * 512, bn_v + i * 512);
        maxpool_kernel<<<(int)(((ll)nbc * L2 * 512 + 255) / 256), 256, 0, stream>>>(
            P0, X + (ll)bp * nbc * L2 * 512, L, L2, nbc);
      }
    }
  }

  ln_kernel<<<8 * 256, 256, 0, stream>>>(X, nullptr, nullptr, 256, enc_g, enc_b, out + 80);
  pred_kernel<<<40, 64, 0, stream>>>(dec_bv, head_w, head_b, out);
}

// Round 19
// 7187.645 us; speedup vs baseline: 1.0850x; 1.0850x over previous
//
#include <hip/hip_runtime.h>
#include <hip/hip_bf16.h>
#include <math.h>
#include <stdint.h>

typedef long long ll;

// ---------------- threefry2x32 (20 rounds, JAX/Random123 exact) ----------------
__host__ __device__ inline uint32_t rotl32(uint32_t v, int d) { return (v << d) | (v >> (32 - d)); }

#define TF_R4(a, b, c, d)                              \
  x0 += x1; x1 = rotl32(x1, a); x1 ^= x0;              \
  x0 += x1; x1 = rotl32(x1, b); x1 ^= x0;              \
  x0 += x1; x1 = rotl32(x1, c); x1 ^= x0;              \
  x0 += x1; x1 = rotl32(x1, d); x1 ^= x0;

__host__ __device__ inline void threefry(uint32_t k0, uint32_t k1, uint32_t x0, uint32_t x1,
                                         uint32_t* o0, uint32_t* o1) {
  uint32_t ks2 = k0 ^ k1 ^ 0x1BD11BDAu;
  x0 += k0; x1 += k1;
  TF_R4(13, 15, 26, 6)
  x0 += k1; x1 += ks2 + 1u;
  TF_R4(17, 29, 16, 24)
  x0 += ks2; x1 += k0 + 2u;
  TF_R4(13, 15, 26, 6)
  x0 += k0; x1 += k1 + 3u;
  TF_R4(17, 29, 16, 24)
  x0 += k1; x1 += ks2 + 4u;
  TF_R4(13, 15, 26, 6)
  x0 += ks2; x1 += k0 + 5u;
  *o0 = x0; *o1 = x1;
}

__device__ __forceinline__ float pe_val(int pos, int d) {
  int k2 = (d >> 1) << 1;
  float div = expf((float)k2 * (-9.210340371976184f / 512.0f));
  float arg = (float)pos * div;
  return (d & 1) ? cosf(arg) : sinf(arg);
}

// ---------------- kernels ----------------

// R18b: precompute pe table [2048][512] once (identical pe_val floats) into SC1.
__global__ __launch_bounds__(256) void pe_kernel(float* __restrict__ PE) {
  ll i = (ll)blockIdx.x * 256 + threadIdx.x;
  if (i >= (ll)2048 * 512) return;
  int d = (int)(i & 511);
  int l = (int)(i >> 9);
  PE[i] = pe_val(l, d);
}

// embed nb batches starting at b0 into out (local rows); pe from precomputed table
// (same float values as pe_val -> bitwise-identical X).
__global__ __launch_bounds__(256) void embed_kernel(const float* __restrict__ src,
                                                    const float* __restrict__ in_w,
                                                    const float* __restrict__ in_b,
                                                    const float* __restrict__ PE,
                                                    int b0, int nb, float* __restrict__ out) {
  ll i = (ll)blockIdx.x * 256 + threadIdx.x;
  if (i >= (ll)nb * 2048 * 512) return;
  int d = (int)(i & 511);
  ll r = i >> 9;
  int l = (int)(r & 2047);
  int b = b0 + (int)(r >> 11);
  float acc = in_b[d];
#pragma unroll
  for (int j = 0; j < 6; j++)
    acc = fmaf(src[((ll)b * 2048 + l) * 6 + j], in_w[j * 512 + d], acc);
  acc += PE[(ll)l * 512 + d];
  out[i] = acc;
}

// R16b: LDS-tiled transpose of conv weights [o][i][tap] -> [tap][i][o].
// Coalesced load and store; 65-stride pad kills bank conflicts. Values only move;
// gemm's Bs contents are identical -> bitwise-identical conv outputs.
__global__ __launch_bounds__(256) void wt_kernel(const float* __restrict__ W,
                                                 float* __restrict__ WT,
                                                 ll srcOff) {
  __shared__ float tile[64][65];
  int o0 = blockIdx.x * 64, c0 = blockIdx.y * 64;
  int t = threadIdx.x;
  int g = t >> 6, l = t & 63;   // g:0..3, l:0..63
#pragma unroll 4
  for (int jj = 0; jj < 16; jj++) {
    int r = g * 16 + jj;
    tile[r][l] = W[srcOff + (ll)(o0 + r) * 1536 + (c0 + l)];
  }
  __syncthreads();
#pragma unroll 4
  for (int jj = 0; jj < 16; jj++) {
    int c = g * 16 + jj;
    int gc = c0 + c;
    int tap = gc % 3, k = gc / 3;
    WT[(ll)tap * 262144 + (ll)k * 512 + (o0 + l)] = tile[l][c];
  }
}

// 64x64-tile GEMM, 256 threads, 4x4 acc. C local rows. Grid (M/64, N/64).
// Verified R10/R11/R13: BK=32 single buffer. Load idiom: float4 locals ->
// member-wise LDS stores; NO structs / NO address-of-register (R4-R8 scratch
// catastrophe). R16b wTapStride: transposed [tap][k][n] takes vectorized path
// (verified R17: -374us). fuse: 0 none, 1 gelu, 2 BN+ELU.
__global__ __launch_bounds__(256, 4) void gemm_kernel(
    const float* __restrict__ A, int mBase, int L, int K,
    const float* __restrict__ W, ll wOffBase, int wSK, int wSN, int wTapStride,
    const float* __restrict__ bias, float* __restrict__ C, int N,
    int taps, int shiftMode, int fuse,
    const float* __restrict__ bn_g, const float* __restrict__ bn_b,
    const float* __restrict__ bn_m, const float* __restrict__ bn_v) {
  __shared__ float As[32][68];
  __shared__ float Bs[32][64];
  const int tid = threadIdx.x;
  const int tx = tid & 15, ty = tid >> 4;     // tx: 4 cols, ty: 4 rows
  const int m0 = blockIdx.x * 64, n0 = blockIdx.y * 64;
  const int rA = tid >> 2;                    // 0..63 loader row
  const int kA = (tid & 3) << 3;              // 0,8,16,24 (8 k per thread, 2 float4)
  const int kB = tid >> 4, nB0 = (tid & 15) << 2;  // B rows kB and kB+16

  float acc[4][4] = {};

  for (int tp = 0; tp < taps; tp++) {
    int shift = (taps == 3) ? tp - 1 : 0;
    int gRow = mBase + m0 + rA;
    int b = gRow / L, l = gRow - b * L;
    int l2 = l + shift;
    bool valid = true;
    if (shiftMode == 1) { valid = (l2 >= 0 && l2 < L); if (!valid) l2 = 0; }
    else if (shiftMode == 2) { l2 = l2 < 0 ? l2 + L : (l2 >= L ? l2 - L : l2); }
    const float* aRow = A + (ll)(b * L + l2) * K;
    const ll wOff = wOffBase + (taps == 3 ? (ll)tp * wTapStride : 0);

    for (int k0 = 0; k0 < K; k0 += 32) {
      float4 a0 = make_float4(0.f, 0.f, 0.f, 0.f);
      float4 a1 = make_float4(0.f, 0.f, 0.f, 0.f);
      if (valid) {
        a0 = *(const float4*)(aRow + k0 + kA);
        a1 = *(const float4*)(aRow + k0 + kA + 4);
      }
      As[kA + 0][rA] = a0.x; As[kA + 1][rA] = a0.y;
      As[kA + 2][rA] = a0.z; As[kA + 3][rA] = a0.w;
      As[kA + 4][rA] = a1.x; As[kA + 5][rA] = a1.y;
      As[kA + 6][rA] = a1.z; As[kA + 7][rA] = a1.w;
      if (wSN == 1) {
        *(float4*)&Bs[kB][nB0] = *(const float4*)(W + wOff + (ll)(k0 + kB) * wSK + (n0 + nB0));
        *(float4*)&Bs[kB + 16][nB0] = *(const float4*)(W + wOff + (ll)(k0 + kB + 16) * wSK + (n0 + nB0));
      } else {
#pragma unroll
        for (int j = 0; j < 4; j++)
          Bs[kB][nB0 + j] = W[wOff + (ll)(k0 + kB) * wSK + (ll)(n0 + nB0 + j) * wSN];
#pragma unroll
        for (int j = 0; j < 4; j++)
          Bs[kB + 16][nB0 + j] = W[wOff + (ll)(k0 + kB + 16) * wSK + (ll)(n0 + nB0 + j) * wSN];
      }
      __syncthreads();
#pragma unroll
      for (int kk = 0; kk < 32; kk++) {
        float4 w4 = *(const float4*)&Bs[kk][tx << 2];
        float4 a4 = *(const float4*)&As[kk][ty << 2];
        acc[0][0] = fmaf(a4.x, w4.x, acc[0][0]); acc[0][1] = fmaf(a4.x, w4.y, acc[0][1]);
        acc[0][2] = fmaf(a4.x, w4.z, acc[0][2]); acc[0][3] = fmaf(a4.x, w4.w, acc[0][3]);
        acc[1][0] = fmaf(a4.y, w4.x, acc[1][0]); acc[1][1] = fmaf(a4.y, w4.y, acc[1][1]);
        acc[1][2] = fmaf(a4.y, w4.z, acc[1][2]); acc[1][3] = fmaf(a4.y, w4.w, acc[1][3]);
        acc[2][0] = fmaf(a4.z, w4.x, acc[2][0]); acc[2][1] = fmaf(a4.z, w4.y, acc[2][1]);
        acc[2][2] = fmaf(a4.z, w4.z, acc[2][2]); acc[2][3] = fmaf(a4.z, w4.w, acc[2][3]);
        acc[3][0] = fmaf(a4.w, w4.x, acc[3][0]); acc[3][1] = fmaf(a4.w, w4.y, acc[3][1]);
        acc[3][2] = fmaf(a4.w, w4.z, acc[3][2]); acc[3][3] = fmaf(a4.w, w4.w, acc[3][3]);
      }
      __syncthreads();
    }
  }

  float4 bv = make_float4(0.f, 0.f, 0.f, 0.f);
  if (bias) bv = *(const float4*)(bias + n0 + (tx << 2));
  float4 g4, b4, m4, v4;
  if (fuse == 2) {
    g4 = *(const float4*)(bn_g + n0 + (tx << 2));
    b4 = *(const float4*)(bn_b + n0 + (tx << 2));
    m4 = *(const float4*)(bn_m + n0 + (tx << 2));
    v4 = *(const float4*)(bn_v + n0 + (tx << 2));
    v4.x = 1.f / sqrtf(v4.x + 1e-5f); v4.y = 1.f / sqrtf(v4.y + 1e-5f);
    v4.z = 1.f / sqrtf(v4.z + 1e-5f); v4.w = 1.f / sqrtf(v4.w + 1e-5f);
  }
#pragma unroll
  for (int i = 0; i < 4; i++) {
    int m = m0 + (ty << 2) + i;
    float4 v;
    v.x = acc[i][0] + bv.x; v.y = acc[i][1] + bv.y;
    v.z = acc[i][2] + bv.z; v.w = acc[i][3] + bv.w;
    if (fuse == 1) {
      v.x = 0.5f * v.x * (1.f + erff(v.x * 0.70710678118654752f));
      v.y = 0.5f * v.y * (1.f + erff(v.y * 0.70710678118654752f));
      v.z = 0.5f * v.z * (1.f + erff(v.z * 0.70710678118654752f));
      v.w = 0.5f * v.w * (1.f + erff(v.w * 0.70710678118654752f));
    } else if (fuse == 2) {
      v.x = (v.x - m4.x) * v4.x * g4.x + b4.x; v.x = v.x > 0.f ? v.x : expm1f(v.x);
      v.y = (v.y - m4.y) * v4.y * g4.y + b4.y; v.y = v.y > 0.f ? v.y : expm1f(v.y);
      v.z = (v.z - m4.z) * v4.z * g4.z + b4.z; v.z = v.z > 0.f ? v.z : expm1f(v.z);
      v.w = (v.w - m4.w) * v4.w * g4.w + b4.w; v.w = v.w > 0.f ? v.w : expm1f(v.w);
    }
    *(float4*)(C + (ll)m * N + n0 + (tx << 2)) = v;
  }
}

// merged q/k/v projection for one head, 64x64 tile: grid (rows/64, 3)
__global__ __launch_bounds__(256, 4) void qkv_kernel(
    const float* __restrict__ X,
    const float* __restrict__ wq, const float* __restrict__ wk, const float* __restrict__ wv,
    ll wOff,
    const float* __restrict__ bq, const float* __restrict__ bk, const float* __restrict__ bv,
    float* __restrict__ QH, float* __restrict__ KH, float* __restrict__ VH) {
  const float* W; const float* bias; float* C;
  if (blockIdx.y == 0) { W = wq; bias = bq; C = QH; }
  else if (blockIdx.y == 1) { W = wk; bias = bk; C = KH; }
  else { W = wv; bias = bv; C = VH; }
  __shared__ float As[32][68];
  __shared__ float Bs[32][64];
  const int tid = threadIdx.x;
  const int tx = tid & 15, ty = tid >> 4;
  const int m0 = blockIdx.x * 64;
  const int rA = tid >> 2;
  const int kA = (tid & 3) << 3;
  const int kB = tid >> 4, nB0 = (tid & 15) << 2;
  const float* aRow = X + (ll)(m0 + rA) * 512;

  float acc[4][4] = {};
  for (int k0 = 0; k0 < 512; k0 += 32) {
    float4 a0 = *(const float4*)(aRow + k0 + kA);
    float4 a1 = *(const float4*)(aRow + k0 + kA + 4);
    As[kA + 0][rA] = a0.x; As[kA + 1][rA] = a0.y;
    As[kA + 2][rA] = a0.z; As[kA + 3][rA] = a0.w;
    As[kA + 4][rA] = a1.x; As[kA + 5][rA] = a1.y;
    As[kA + 6][rA] = a1.z; As[kA + 7][rA] = a1.w;
    *(float4*)&Bs[kB][nB0] = *(const float4*)(W + wOff + (ll)(k0 + kB) * 512 + nB0);
    *(float4*)&Bs[kB + 16][nB0] = *(const float4*)(W + wOff + (ll)(k0 + kB + 16) * 512 + nB0);
    __syncthreads();
#pragma unroll
    for (int kk = 0; kk < 32; kk++) {
      float4 w4 = *(const float4*)&Bs[kk][tx << 2];
      float4 a4 = *(const float4*)&As[kk][ty << 2];
      acc[0][0] = fmaf(a4.x, w4.x, acc[0][0]); acc[0][1] = fmaf(a4.x, w4.y, acc[0][1]);
      acc[0][2] = fmaf(a4.x, w4.z, acc[0][2]); acc[0][3] = fmaf(a4.x, w4.w, acc[0][3]);
      acc[1][0] = fmaf(a4.y, w4.x, acc[1][0]); acc[1][1] = fmaf(a4.y, w4.y, acc[1][1]);
      acc[1][2] = fmaf(a4.y, w4.z, acc[1][2]); acc[1][3] = fmaf(a4.y, w4.w, acc[1][3]);
      acc[2][0] = fmaf(a4.z, w4.x, acc[2][0]); acc[2][1] = fmaf(a4.z, w4.y, acc[2][1]);
      acc[2][2] = fmaf(a4.z, w4.z, acc[2][2]); acc[2][3] = fmaf(a4.z, w4.w, acc[2][3]);
      acc[3][0] = fmaf(a4.w, w4.x, acc[3][0]); acc[3][1] = fmaf(a4.w, w4.y, acc[3][1]);
      acc[3][2] = fmaf(a4.w, w4.z, acc[3][2]); acc[3][3] = fmaf(a4.w, w4.w, acc[3][3]);
    }
    __syncthreads();
  }
  float4 bv4 = *(const float4*)(bias + (tx << 2));
#pragma unroll
  for (int i = 0; i < 4; i++) {
    int m = m0 + (ty << 2) + i;
    float4 v;
    v.x = acc[i][0] + bv4.x; v.y = acc[i][1] + bv4.y;
    v.z = acc[i][2] + bv4.z; v.w = acc[i][3] + bv4.w;
    *(float4*)(C + (ll)m * 64 + (tx << 2)) = v;
  }
}

// JAX randint (pow2 span), partitionable mode: bits[m] = o0(k2;0,m)^o1(k2;0,m)
__global__ void idx_kernel(int* __restrict__ idx, uint32_t k0, uint32_t k1, int n, int mask) {
  int m = blockIdx.x * 256 + threadIdx.x;
  if (m < n) {
    uint32_t o0, o1;
    threefry(k0, k1, 0u, (uint32_t)m, &o0, &o1);
    idx[m] = (int)((o0 ^ o1) & (uint32_t)mask);
  }
}

// M[b,l] = max_u(q.k_samp) - sum_u(q.k_samp)/L
// R15/R16: 8-way ILP (verified; gather-bound now — axis closed). Bitwise-identical M.
__global__ __launch_bounds__(256) void m_kernel(const float* __restrict__ Q,
                                                const float* __restrict__ Kk,
                                                const int* __restrict__ idx,
                                                float* __restrict__ M, int L, int U) {
  int wid = (int)(((ll)blockIdx.x * 256 + threadIdx.x) >> 6);
  int lane = threadIdx.x & 63;
  if (wid >= 8 * L) return;
  int b = wid / L, l = wid - b * L;
  float qv = Q[((ll)(b * L + l)) * 64 + lane];
  float mx = -INFINITY, sm = 0.f;
  const int* ip = idx + (ll)l * U;
  int uu = 0;
  for (; uu + 8 <= U; uu += 8) {
    int kr0 = ip[uu] & (L - 1);
    int kr1 = ip[uu + 1] & (L - 1);
    int kr2 = ip[uu + 2] & (L - 1);
    int kr3 = ip[uu + 3] & (L - 1);
    int kr4 = ip[uu + 4] & (L - 1);
    int kr5 = ip[uu + 5] & (L - 1);
    int kr6 = ip[uu + 6] & (L - 1);
    int kr7 = ip[uu + 7] & (L - 1);
    float p0 = qv * Kk[((ll)(b * L + kr0)) * 64 + lane];
    float p1 = qv * Kk[((ll)(b * L + kr1)) * 64 + lane];
    float p2 = qv * Kk[((ll)(b * L + kr2)) * 64 + lane];
    float p3 = qv * Kk[((ll)(b * L + kr3)) * 64 + lane];
    float p4 = qv * Kk[((ll)(b * L + kr4)) * 64 + lane];
    float p5 = qv * Kk[((ll)(b * L + kr5)) * 64 + lane];
    float p6 = qv * Kk[((ll)(b * L + kr6)) * 64 + lane];
    float p7 = qv * Kk[((ll)(b * L + kr7)) * 64 + lane];
#pragma unroll
    for (int d = 32; d > 0; d >>= 1) {
      p0 += __shfl_xor(p0, d);
      p1 += __shfl_xor(p1, d);
      p2 += __shfl_xor(p2, d);
      p3 += __shfl_xor(p3, d);
      p4 += __shfl_xor(p4, d);
      p5 += __shfl_xor(p5, d);
      p6 += __shfl_xor(p6, d);
      p7 += __shfl_xor(p7, d);
    }
    mx = fmaxf(mx, p0); sm += p0;
    mx = fmaxf(mx, p1); sm += p1;
    mx = fmaxf(mx, p2); sm += p2;
    mx = fmaxf(mx, p3); sm += p3;
    mx = fmaxf(mx, p4); sm += p4;
    mx = fmaxf(mx, p5); sm += p5;
    mx = fmaxf(mx, p6); sm += p6;
    mx = fmaxf(mx, p7); sm += p7;
  }
  for (; uu + 4 <= U; uu += 4) {
    int kr0 = ip[uu] & (L - 1);
    int kr1 = ip[uu + 1] & (L - 1);
    int kr2 = ip[uu + 2] & (L - 1);
    int kr3 = ip[uu + 3] & (L - 1);
    float p0 = qv * Kk[((ll)(b * L + kr0)) * 64 + lane];
    float p1 = qv * Kk[((ll)(b * L + kr1)) * 64 + lane];
    float p2 = qv * Kk[((ll)(b * L + kr2)) * 64 + lane];
    float p3 = qv * Kk[((ll)(b * L + kr3)) * 64 + lane];
#pragma unroll
    for (int d = 32; d > 0; d >>= 1) {
      p0 += __shfl_xor(p0, d);
      p1 += __shfl_xor(p1, d);
      p2 += __shfl_xor(p2, d);
      p3 += __shfl_xor(p3, d);
    }
    mx = fmaxf(mx, p0); sm += p0;
    mx = fmaxf(mx, p1); sm += p1;
    mx = fmaxf(mx, p2); sm += p2;
    mx = fmaxf(mx, p3); sm += p3;
  }
  for (; uu + 2 <= U; uu += 2) {
    int kr0 = ip[uu] & (L - 1);
    int kr1 = ip[uu + 1] & (L - 1);
    float p0 = qv * Kk[((ll)(b * L + kr0)) * 64 + lane];
    float p1 = qv * Kk[((ll)(b * L + kr1)) * 64 + lane];
#pragma unroll
    for (int d = 32; d > 0; d >>= 1) {
      p0 += __shfl_xor(p0, d);
      p1 += __shfl_xor(p1, d);
    }
    mx = fmaxf(mx, p0); sm += p0;
    mx = fmaxf(mx, p1); sm += p1;
  }
  if (uu < U) {
    int kr = ip[uu] & (L - 1);
    float p = qv * Kk[((ll)(b * L + kr)) * 64 + lane];
#pragma unroll
    for (int d = 32; d > 0; d >>= 1) p += __shfl_xor(p, d);
    mx = fmaxf(mx, p);
    sm += p;
  }
  if (lane == 0) M[(ll)b * L + l] = mx - sm / (float)L;
}

// fused: topk + qgather + vmean; one block per b.
template <int NRT>
__global__ __launch_bounds__(256) void tgv_kernel(const float* __restrict__ M,
                                                  const float* __restrict__ Q,
                                                  const float* __restrict__ V,
                                                  int* __restrict__ topi,
                                                  float* __restrict__ QR,
                                                  float* __restrict__ vm, int L, int u) {
  __shared__ unsigned long long wbest[2][4];
  __shared__ int rows[40];
  __shared__ float s4[4][64];
  int b = blockIdx.x, t = threadIdx.x;
  int lane = t & 63, w = t >> 6;
  ll base = (ll)b * L;
  float v8[NRT];
#pragma unroll
  for (int i = 0; i < NRT; i++) v8[i] = M[base + t + (i << 8)];
  for (int j = 0; j < u; j++) {
    float bv = v8[0]; int bi = t;
#pragma unroll
    for (int i = 1; i < NRT; i++) {
      if (v8[i] > bv) { bv = v8[i]; bi = t + (i << 8); }
    }
    uint32_t mu = __float_as_uint(bv);
    mu = (mu & 0x80000000u) ? ~mu : (mu | 0x80000000u);
    unsigned long long key = ((unsigned long long)mu << 32) | (uint32_t)(~bi);
#pragma unroll
    for (int d = 32; d > 0; d >>= 1) {
      unsigned long long o = __shfl_xor(key, d);
      key = o > key ? o : key;
    }
    if (lane == 0) wbest[j & 1][w] = key;
    __syncthreads();
    unsigned long long k0 = wbest[j & 1][0], k1 = wbest[j & 1][1];
    unsigned long long k2 = wbest[j & 1][2], k3 = wbest[j & 1][3];
    unsigned long long kb = k0 > k1 ? k0 : k1;
    unsigned long long kc = k2 > k3 ? k2 : k3;
    if (kc > kb) kb = kc;
    int wi = (int)(~(uint32_t)kb);
#pragma unroll
    for (int i = 0; i < NRT; i++)
      if (wi == t + (i << 8)) v8[i] = -INFINITY;
    if (t == 0) { topi[(ll)b * u + j] = wi; rows[j] = wi; }
  }
  __syncthreads();
  for (int idx = t; idx < u * 64; idx += 256) {
    int j = idx >> 6, e = idx & 63;
    int row = rows[j];
    QR[((ll)b * u + j) * 64 + e] = Q[((ll)(b * L + row)) * 64 + e];
  }
  int e = t & 63, p2 = t >> 6;
  float acc = 0.f;
  for (int l = p2; l < L; l += 4) acc += V[((ll)(b * L + l)) * 64 + e];
  s4[p2][e] = acc;
  __syncthreads();
  if (t < 64)
    vm[(ll)b * 64 + t] = (s4[0][t] + s4[1][t] + s4[2][t] + s4[3][t]) / (float)L;
}

// ---- chunked attention (R17-verified form; R18's (8,C) amortization regressed
// +528us — occupancy beats traffic amortization, thrice-confirmed; family closed) ----

// attna: grid (8u, C). scores for 256 l's of one query row + chunk max.
__global__ __launch_bounds__(256) void attna_kernel(const float* __restrict__ QR,
                                                    const float* __restrict__ Kk,
                                                    float* __restrict__ SCb,
                                                    float* __restrict__ MX,
                                                    int L, int u) {
  int g = blockIdx.x, c = blockIdx.y;
  int b = g / u;
  __shared__ float qs[64];
  __shared__ float wmax[4];
  int t = threadIdx.x;
  if (t < 64) qs[t] = QR[(ll)g * 64 + t];
  __syncthreads();
  int l = (c << 8) + t;
  const float4* kr = (const float4*)(Kk + ((ll)(b * L + l)) * 64);
  float d = 0.f;
#pragma unroll
  for (int e = 0; e < 16; e++) {
    float4 k4 = kr[e];
    float4 q4 = *(const float4*)&qs[e << 2];
    d = fmaf(q4.x, k4.x, d);
    d = fmaf(q4.y, k4.y, d);
    d = fmaf(q4.z, k4.z, d);
    d = fmaf(q4.w, k4.w, d);
  }
  d *= 0.125f;
  SCb[(ll)g * L + l] = d;
  float m = d;
#pragma unroll
  for (int s = 32; s > 0; s >>= 1) m = fmaxf(m, __shfl_xor(m, s));
  if ((t & 63) == 0) wmax[t >> 6] = m;
  __syncthreads();
  if (t == 0)
    MX[g * 8 + c] = fmaxf(fmaxf(wmax[0], wmax[1]), fmaxf(wmax[2], wmax[3]));
}

// attnb: grid (8u, C). exp(sc-mx), chunk denom, chunk PV partial.
__global__ __launch_bounds__(256) void attnb_kernel(const float* __restrict__ SCb,
                                                    const float* __restrict__ MX,
                                                    const float* __restrict__ V,
                                                    float* __restrict__ PUPD,
                                                    float* __restrict__ PSUM,
                                                    int L, int u, int C) {
  int g = blockIdx.x, c = blockIdx.y;
  int b = g / u;
  __shared__ float evs[256];
  __shared__ float red[256];
  __shared__ float upds[4][64];
  int t = threadIdx.x;
  float mx = MX[g * 8];
  for (int j = 1; j < C; j++) mx = fmaxf(mx, MX[g * 8 + j]);
  int l = (c << 8) + t;
  float ev = expf(SCb[(ll)g * L + l] - mx);
  evs[t] = ev;
  red[t] = ev;
  __syncthreads();
  for (int s = 128; s > 0; s >>= 1) { if (t < s) red[t] += red[t + s]; __syncthreads(); }
  int e = t & 63, p2 = t >> 6;
  const float* vb = V + ((ll)(b * L + (c << 8))) * 64;
  float partial = 0.f;
#pragma unroll 4
  for (int i = 0; i < 64; i++) {
    int lidx = p2 + (i << 2);
    partial = fmaf(evs[lidx], vb[(ll)lidx * 64 + e], partial);
  }
  upds[p2][e] = partial;
  __syncthreads();
  if (t < 64) {
    PUPD[((ll)(g * 8 + c)) * 64 + t] = upds[0][t] + upds[1][t] + upds[2][t] + upds[3][t];
    if (t == 0) PSUM[g * 8 + c] = red[0];
  }
}

// attnc: grid (8u), 64 threads: combine C chunks -> upd row.
__global__ __launch_bounds__(64) void attnc_kernel(const float* __restrict__ PUPD,
                                                   const float* __restrict__ PSUM,
                                                   float* __restrict__ upd, int C) {
  int g = blockIdx.x, t = threadIdx.x;
  float den = 0.f, val = 0.f;
  for (int c = 0; c < C; c++) {
    den += PSUM[g * 8 + c];
    val += PUPD[((ll)(g * 8 + c)) * 64 + t];
  }
  upd[(ll)g * 64 + t] = val * (1.f / den);
}

// BR[b,t] = bo[t] + sum_{h,e} VM[(h*8+b)*64+e] * Wo[wOff + (h*64+e)*512 + t]
__global__ __launch_bounds__(512) void baserow_kernel(const float* __restrict__ VM,
                                                      const float* __restrict__ Wo, ll wOff,
                                                      const float* __restrict__ bo,
                                                      float* __restrict__ BR) {
  int b = blockIdx.x, t = threadIdx.x;
  float acc = bo[t];
  for (int h = 0; h < 8; h++)
#pragma unroll 4
    for (int e = 0; e < 64; e++)
      acc = fmaf(VM[(ll)(h * 8 + b) * 64 + e], Wo[wOff + (ll)(h * 64 + e) * 512 + t], acc);
  BR[(ll)b * 512 + t] = acc;
}

// X[b, topi] += (upd - vm) @ Wo_h ; atomicAdd (rows may repeat across heads)
__global__ __launch_bounds__(512) void corr_kernel(const float* __restrict__ UPD,
                                                   const float* __restrict__ VM,
                                                   const int* __restrict__ topi,
                                                   const float* __restrict__ Wo, ll wOff,
                                                   float* __restrict__ X, int L, int u) {
  int g = blockIdx.x;
  int h = g / (8 * u);
  int r = g - h * 8 * u;
  int b = r / u;
  int row = topi[g] & (L - 1);
  int t = threadIdx.x;
  float c = 0.f;
#pragma unroll 4
  for (int e = 0; e < 64; e++) {
    float dv = UPD[(ll)g * 64 + e] - VM[(ll)(h * 8 + b) * 64 + e];
    c = fmaf(dv, Wo[wOff + (ll)(h * 64 + e) * 512 + t], c);
  }
  atomicAdd(&X[((ll)b * L + row) * 512 + t], c);
}

// layernorm over 512 of (x [+res] [+br(b)]); br is per-batch row (B x 512), b = row/L
__global__ __launch_bounds__(256) void ln_kernel(const float* __restrict__ x,
                                                 const float* __restrict__ res,
                                                 const float* __restrict__ br, int L,
                                                 const float* __restrict__ g,
                                                 const float* __restrict__ be,
                                                 float* __restrict__ out) {
  ll base = (ll)blockIdx.x * 512;
  int t = threadIdx.x;
  float v0 = x[base + t], v1 = x[base + 256 + t];
  if (res) { v0 += res[base + t]; v1 += res[base + 256 + t]; }
  if (br) {
    int b = blockIdx.x / L;
    v0 += br[(ll)b * 512 + t];
    v1 += br[(ll)b * 512 + 256 + t];
  }
  __shared__ float red[256];
  red[t] = v0 + v1;
  __syncthreads();
  for (int s = 128; s > 0; s >>= 1) { if (t < s) red[t] += red[t + s]; __syncthreads(); }
  float mu = red[0] * (1.f / 512.f);
  __syncthreads();
  float d0 = v0 - mu, d1 = v1 - mu;
  red[t] = d0 * d0 + d1 * d1;
  __syncthreads();
  for (int s = 128; s > 0; s >>= 1) { if (t < s) red[t] += red[t + s]; __syncthreads(); }
  float rstd = 1.f / sqrtf(red[0] * (1.f / 512.f) + 1e-5f);
  out[base + t] = d0 * rstd * g[t] + be[t];
  out[base + 256 + t] = d1 * rstd * g[t + 256] + be[t + 256];
}

// maxpool over nb local batches
__global__ __launch_bounds__(256) void maxpool_kernel(const float* __restrict__ y,
                                                      float* __restrict__ outp,
                                                      int L, int L2, int nb) {
  ll n = (ll)nb * L2 * 512;
  ll i = (ll)blockIdx.x * 256 + threadIdx.x;
  if (i >= n) return;
  int per = L2 * 512;
  int bb = (int)(i / per);
  int rem = (int)(i - (ll)bb * per);
  int c = rem & 511;
  int l2 = rem >> 9;
  int l0 = 2 * l2 - 1;
  float m = -INFINITY;
#pragma unroll
  for (int w = 0; w < 3; w++) {
    int l = l0 + w;
    if (l >= 0 && l < L) m = fmaxf(m, y[((ll)bb * L + l) * 512 + c]);
  }
  outp[i] = m;
}

// pred rows t=5..9
__global__ __launch_bounds__(64) void pred_kernel(const float* __restrict__ dec_b,
                                                  const float* __restrict__ head_w,
                                                  const float* __restrict__ head_b,
                                                  float* __restrict__ out) {
  int b = blockIdx.x / 5, tt = blockIdx.x % 5, t = 5 + tt;
  int lane = threadIdx.x;
  float a0 = 0.f, a1 = 0.f;
  for (int d = lane; d < 512; d += 64) {
    float td = dec_b[d] + pe_val(t, d) + pe_val(b, d);
    a0 = fmaf(td, head_w[2 * d], a0);
    a1 = fmaf(td, head_w[2 * d + 1], a1);
  }
#pragma unroll
  for (int s = 32; s > 0; s >>= 1) { a0 += __shfl_xor(a0, s); a1 += __shfl_xor(a1, s); }
  if (lane == 0) {
    out[(ll)b * 10 + tt * 2 + 0] = a0 + head_b[0];
    out[(ll)b * 10 + tt * 2 + 1] = a1 + head_b[1];
  }
}

// ---------------- host ----------------
extern "C" void kernel_launch(void* const* d_in, const int* in_sizes, int n_in,
                              void* d_out, int out_size, void* d_ws, size_t ws_size,
                              hipStream_t stream) {
  if (n_in < 34) return;
  if (in_sizes[0] != 8 * 2048 * 6) return;
  if (in_sizes[4] != 512 * 512 * 3) return;
  if (in_sizes[6] != 4 * 512 * 512) return;
  if (in_sizes[22] != 3 * 512 * 512 * 3) return;
  if (in_sizes[33] != 2) return;
  if (ws_size < 55700000) return;

  const ll BIG = (ll)8 * 2048 * 512;
  const ll HSZ = (ll)8 * 2048 * 64;
  const ll CSZ = (ll)2048 * 512;

  const float* src    = (const float*)d_in[0];
  const float* in_w   = (const float*)d_in[2];
  const float* in_b   = (const float*)d_in[3];
  const float* conv_w = (const float*)d_in[4];
  const float* conv_b = (const float*)d_in[5];
  const float* wq = (const float*)d_in[6];
  const float* bq = (const float*)d_in[7];
  const float* wk = (const float*)d_in[8];
  const float* bk = (const float*)d_in[9];
  const float* wv = (const float*)d_in[10];
  const float* bv = (const float*)d_in[11];
  const float* wo = (const float*)d_in[12];
  const float* bo = (const float*)d_in[13];
  const float* n1_g = (const float*)d_in[14];
  const float* n1_b = (const float*)d_in[15];
  const float* ff1_w = (const float*)d_in[16];
  const float* ff1_b = (const float*)d_in[17];
  const float* ff2_w = (const float*)d_in[18];
  const float* ff2_b = (const float*)d_in[19];
  const float* n2_g = (const float*)d_in[20];
  const float* n2_b = (const float*)d_in[21];
  const float* dconv_w = (const float*)d_in[22];
  const float* dconv_b = (const float*)d_in[23];
  const float* bn_g = (const float*)d_in[24];
  const float* bn_b = (const float*)d_in[25];
  const float* bn_m = (const float*)d_in[26];
  const float* bn_v = (const float*)d_in[27];
  const float* enc_g = (const float*)d_in[28];
  const float* enc_b = (const float*)d_in[29];
  const float* dec_bv = (const float*)d_in[31];
  const float* head_w = (const float*)d_in[32];
  const float* head_b = (const float*)d_in[33];
  float* out = (float*)d_out;

  char* p = (char*)d_ws;
  float* X  = (float*)p; p += BIG * 4;
  float* QH = (float*)p; p += HSZ * 4;   // pool start
  float* KH = (float*)p; p += HSZ * 4;
  float* VH = (float*)p; p += HSZ * 4;
  float* SC1 = (float*)p; p += CSZ * 4;
  float* SC2 = (float*)p; p += CSZ * 4;
  float* UPD = (float*)p; p += (ll)8 * 8 * 40 * 64 * 4;
  float* VM  = (float*)p; p += (ll)8 * 8 * 64 * 4;
  float* BR  = (float*)p; p += (ll)8 * 512 * 4;
  float* Mh  = (float*)p; p += (ll)8 * 2048 * 4;
  float* QR  = (float*)p; p += (ll)8 * 40 * 64 * 4;
  int* IDX   = (int*)p; p += (ll)2048 * 40 * 4;
  int* TOPIA = (int*)p;

  float* P0 = QH;                       // 4096x512 alias (QH+KH)
  float* P1 = QH + (ll)4096 * 512;      // 4096x512 alias (VH+SC1) — FFN phase only
  // attn scratch (h-loop only; temporally disjoint from P1's FFN use of SC1):
  float* MXf   = SC2;                   // 8u*8
  float* PSUMf = SC2 + 4096;            // 8u*8
  float* PUPDf = SC2 + 8192;            // 8u*8*64
  // transposed conv weights (SC2, conv/distill phases only — disjoint from attn scratch)
  float* WT = SC2;
  // PE table (SC1, embed phase only — disjoint from attn/FFN uses of SC1)
  float* PE = SC1;

  uint32_t keys[4][2];
  for (int i = 0; i < 4; i++) {
    uint32_t K0, K1, g0, g1;
    threefry(0u, 42u, 0u, (uint32_t)i, &K0, &K1);
    threefry(K0, K1, 0u, 1u, &g0, &g1);
    keys[i][0] = g0;
    keys[i][1] = g1;
  }

  // precompute PE table + transpose input conv weights
  pe_kernel<<<4096, 256, 0, stream>>>(PE);
  wt_kernel<<<dim3(8, 24), 256, 0, stream>>>(conv_w, WT, 0);
  // embed + input conv (zero-pad, 3 taps fused), 2 batches per iter through P0
  for (int bp = 0; bp < 4; bp++) {
    embed_kernel<<<(int)((2 * CSZ + 255) / 256), 256, 0, stream>>>(src, in_w, in_b, PE, bp * 2, 2, P0);
    gemm_kernel<<<dim3(64, 8), 256, 0, stream>>>(
        P0, 0, 2048, 512, WT, 0, 512, 1, 262144, conv_b, X + (ll)bp * 2 * CSZ, 512,
        3, 1, 0, nullptr, nullptr, nullptr, nullptr);
  }

  const int Ls[4] = {2048, 1024, 512, 256};
  const int Us[4] = {40, 35, 35, 30};

  for (int i = 0; i < 4; i++) {
    int L = Ls[i], U = Us[i];
    int Mrows = 8 * L;
    int LU = L * U;
    int C = L >> 8;                      // 8,4,2,1 chunks of 256
    ll wOff = (ll)i * 262144;

    idx_kernel<<<(LU + 255) / 256, 256, 0, stream>>>(IDX, keys[i][0], keys[i][1], LU, L - 1);

    for (int h = 0; h < 8; h++) {
      qkv_kernel<<<dim3(Mrows / 64, 3), 256, 0, stream>>>(
          X, wq, wk, wv, wOff + h * 64,
          bq + i * 512 + h * 64, bk + i * 512 + h * 64, bv + i * 512 + h * 64, QH, KH, VH);
      m_kernel<<<(8 * L * 64) / 256, 256, 0, stream>>>(QH, KH, IDX, Mh, L, U);
      if (L == 2048)
        tgv_kernel<8><<<8, 256, 0, stream>>>(Mh, QH, VH, TOPIA + (ll)h * 8 * U, QR,
                                             VM + (ll)h * 8 * 64, L, U);
      else if (L == 1024)
        tgv_kernel<4><<<8, 256, 0, stream>>>(Mh, QH, VH, TOPIA + (ll)h * 8 * U, QR,
                                             VM + (ll)h * 8 * 64, L, U);
      else if (L == 512)
        tgv_kernel<2><<<8, 256, 0, stream>>>(Mh, QH, VH, TOPIA + (ll)h * 8 * U, QR,
                                             VM + (ll)h * 8 * 64, L, U);
      else
        tgv_kernel<1><<<8, 256, 0, stream>>>(Mh, QH, VH, TOPIA + (ll)h * 8 * U, QR,
                                             VM + (ll)h * 8 * 64, L, U);
      attna_kernel<<<dim3(8 * U, C), 256, 0, stream>>>(QR, KH, SC1, MXf, L, U);
      attnb_kernel<<<dim3(8 * U, C), 256, 0, stream>>>(SC1, MXf, VH, PUPDf, PSUMf, L, U, C);
      attnc_kernel<<<8 * U, 64, 0, stream>>>(PUPDf, PSUMf, UPD + (ll)h * 8 * U * 64, C);
    }

    baserow_kernel<<<8, 512, 0, stream>>>(VM, wo, wOff, bo + i * 512, BR);
    corr_kernel<<<64 * U, 512, 0, stream>>>(UPD, VM, TOPIA, wo, wOff, X, L, U);
    // LN1 with BR folded in (X + corr + BR)
    ln_kernel<<<Mrows, 256, 0, stream>>>(X, nullptr, BR, L, n1_g + i * 512, n1_b + i * 512, X);

    // FFN: FF1+gelu -> P0; FF2 -> P1; LN2(X+P1) -> X  (4096-row chunks)
    int CR = Mrows < 4096 ? Mrows : 4096;
    for (int r0 = 0; r0 < Mrows; r0 += CR) {
      gemm_kernel<<<dim3(CR / 64, 8), 256, 0, stream>>>(
          X + (ll)r0 * 512, 0, CR, 512, ff1_w, wOff, 512, 1, 0, ff1_b + i * 512, P0, 512,
          1, 0, 1, nullptr, nullptr, nullptr, nullptr);
      gemm_kernel<<<dim3(CR / 64, 8), 256, 0, stream>>>(
          P0, 0, CR, 512, ff2_w, wOff, 512, 1, 0, ff2_b + i * 512, P1, 512,
          1, 0, 0, nullptr, nullptr, nullptr, nullptr);
      ln_kernel<<<CR, 256, 0, stream>>>(X + (ll)r0 * 512, P1, nullptr, L, n2_g + i * 512,
                                        n2_b + i * 512, X + (ll)r0 * 512);
    }

    if (i < 3) {
      // distill: conv(wrap,3 taps)+BN+ELU fused -> P0; maxpool -> X
      // transpose this layer's dconv weights into SC2 (attn scratch dead here)
      wt_kernel<<<dim3(8, 24), 256, 0, stream>>>(dconv_w, WT, (ll)i * 786432);
      int L2 = L / 2;
      int nbc = 4096 / L; if (nbc > 8) nbc = 8;   // 2, 4, 8
      for (int bp = 0; bp < 8 / nbc; bp++) {
        gemm_kernel<<<dim3((nbc * L) / 64, 8), 256, 0, stream>>>(
            X, bp * nbc * L, L, 512, WT, 0, 512, 1, 262144, dconv_b + i * 512,
            P0, 512, 3, 2, 2, bn_g + i * 512, bn_b + i * 512, bn_m + i * 512, bn_v + i * 512);
        maxpool_kernel<<<(int)(((ll)nbc * L2 * 512 + 255) / 256), 256, 0, stream>>>(
            P0, X + (ll)bp * nbc * L2 * 512, L, L2, nbc);
      }
    }
  }

  ln_kernel<<<8 * 256, 256, 0, stream>>>(X, nullptr, nullptr, 256, enc_g, enc_b, out + 80);
  pred_kernel<<<40, 64, 0, stream>>>(dec_bv, head_w, head_b, out);
}